// Round 1
// baseline (5387.548 us; speedup 1.0000x reference)
//
#include <hip/hip_runtime.h>
#include <math.h>

#define NP 1024
#define DM 256
#define NL 18
#define BT 4

#define LOG2048 7.6246189861593985f
#define LOG1024 6.9314718055994531f

// ---------------- block reductions (blockDim = 256) ----------------
__device__ __forceinline__ float block_reduce_max(float v, float* red) {
    int tid = threadIdx.x;
    red[tid] = v; __syncthreads();
    for (int s = 128; s > 0; s >>= 1) {
        if (tid < s) red[tid] = fmaxf(red[tid], red[tid + s]);
        __syncthreads();
    }
    float r = red[0]; __syncthreads();
    return r;
}
__device__ __forceinline__ float block_reduce_sum(float v, float* red) {
    int tid = threadIdx.x;
    red[tid] = v; __syncthreads();
    for (int s = 128; s > 0; s >>= 1) {
        if (tid < s) red[tid] += red[tid + s];
        __syncthreads();
    }
    float r = red[0]; __syncthreads();
    return r;
}

// ---------------- generic conv1x1 GEMM ----------------
// out[bt,o,n] (=, or += if accumulate) sum_i W[o,i]*in[bt^srcXor, i, n] + bias[o]
// input channels i<split come from X1 (batch stride split*NP), else X2 (stride (I-split)*NP)
__global__ __launch_bounds__(256)
void gemm_conv_kernel(const float* __restrict__ W, const float* __restrict__ bias,
                      const float* __restrict__ X1, const float* __restrict__ X2,
                      float* __restrict__ Out, int O, int I, int split,
                      int srcXor, int accumulate)
{
    __shared__ float As[16][68]; // As[kk][oo]
    __shared__ float Bs[16][68]; // Bs[kk][nn]
    const int bt = blockIdx.z;
    const int btS = bt ^ srcXor;
    const int o0 = blockIdx.y * 64;
    const int n0 = blockIdx.x * 64;
    const int tx = threadIdx.x, ty = threadIdx.y;
    const int tid = ty * 16 + tx;

    const int lw_r = tid >> 2;        // 0..63 (o)
    const int lw_c = (tid & 3) * 4;   // 0..12 (i)
    const int lx_k = tid >> 4;        // 0..15 (i)
    const int lx_n = (tid & 15) * 4;  // 0..60 (n)

    float acc[4][4] = {};

    for (int i0 = 0; i0 < I; i0 += 16) {
        float4 w4 = *(const float4*)&W[(size_t)(o0 + lw_r) * I + i0 + lw_c];
        As[lw_c + 0][lw_r] = w4.x;
        As[lw_c + 1][lw_r] = w4.y;
        As[lw_c + 2][lw_r] = w4.z;
        As[lw_c + 3][lw_r] = w4.w;

        int ig = i0 + lx_k;
        const float* src; size_t off;
        if (ig < split) { src = X1; off = ((size_t)btS * split + ig) * NP; }
        else            { src = X2; off = ((size_t)btS * (I - split) + (ig - split)) * NP; }
        float4 x4 = *(const float4*)&src[off + n0 + lx_n];
        Bs[lx_k][lx_n + 0] = x4.x;
        Bs[lx_k][lx_n + 1] = x4.y;
        Bs[lx_k][lx_n + 2] = x4.z;
        Bs[lx_k][lx_n + 3] = x4.w;

        __syncthreads();
        #pragma unroll
        for (int kk = 0; kk < 16; kk++) {
            float4 a4 = *(const float4*)&As[kk][ty * 4];
            float4 b4 = *(const float4*)&Bs[kk][tx * 4];
            float av[4] = {a4.x, a4.y, a4.z, a4.w};
            float bv[4] = {b4.x, b4.y, b4.z, b4.w};
            #pragma unroll
            for (int i = 0; i < 4; i++)
                #pragma unroll
                for (int j = 0; j < 4; j++)
                    acc[i][j] = fmaf(av[i], bv[j], acc[i][j]);
        }
        __syncthreads();
    }
    #pragma unroll
    for (int i = 0; i < 4; i++) {
        int o = o0 + ty * 4 + i;
        float bi = bias[o];
        #pragma unroll
        for (int j = 0; j < 4; j++) {
            int n = n0 + tx * 4 + j;
            size_t oidx = ((size_t)bt * O + o) * NP + n;
            float v = acc[i][j] + bi;
            if (accumulate) Out[oidx] += v;
            else Out[oidx] = v;
        }
    }
}

// ---------------- attention: S[bh,n,m] = (1/8) sum_d q[4d+h,n] k[4d+h,m] ----------------
__global__ __launch_bounds__(256)
void qk_kernel(const float* __restrict__ Q, const float* __restrict__ K, float* __restrict__ S)
{
    __shared__ float Qs[16][68];
    __shared__ float Ks[16][68];
    const int bh = blockIdx.z;
    const int bt = bh >> 2, h = bh & 3;
    const int n0 = blockIdx.x * 64, m0 = blockIdx.y * 64;
    const int tx = threadIdx.x, ty = threadIdx.y;
    const int tid = ty * 16 + tx;
    const int ld_d = tid >> 4;
    const int ld_c = (tid & 15) * 4;
    float acc[4][4] = {};
    for (int d0 = 0; d0 < 64; d0 += 16) {
        int ch = 4 * (d0 + ld_d) + h;
        float4 q4 = *(const float4*)&Q[((size_t)bt * DM + ch) * NP + n0 + ld_c];
        float4 k4 = *(const float4*)&K[((size_t)bt * DM + ch) * NP + m0 + ld_c];
        Qs[ld_d][ld_c + 0] = q4.x; Qs[ld_d][ld_c + 1] = q4.y;
        Qs[ld_d][ld_c + 2] = q4.z; Qs[ld_d][ld_c + 3] = q4.w;
        Ks[ld_d][ld_c + 0] = k4.x; Ks[ld_d][ld_c + 1] = k4.y;
        Ks[ld_d][ld_c + 2] = k4.z; Ks[ld_d][ld_c + 3] = k4.w;
        __syncthreads();
        #pragma unroll
        for (int kk = 0; kk < 16; kk++) {
            float4 a4 = *(const float4*)&Qs[kk][ty * 4];
            float4 b4 = *(const float4*)&Ks[kk][tx * 4];
            float av[4] = {a4.x, a4.y, a4.z, a4.w};
            float bv[4] = {b4.x, b4.y, b4.z, b4.w};
            #pragma unroll
            for (int i = 0; i < 4; i++)
                #pragma unroll
                for (int j = 0; j < 4; j++)
                    acc[i][j] = fmaf(av[i], bv[j], acc[i][j]);
        }
        __syncthreads();
    }
    float* Sb = S + (size_t)bh * NP * NP;
    #pragma unroll
    for (int i = 0; i < 4; i++)
        #pragma unroll
        for (int j = 0; j < 4; j++)
            Sb[(size_t)(n0 + ty * 4 + i) * NP + m0 + tx * 4 + j] = acc[i][j] * 0.125f;
}

// ---------------- softmax over last dim (row length 1024), in place ----------------
__global__ __launch_bounds__(256)
void softmax_kernel(float* __restrict__ S)
{
    __shared__ float red[256];
    const size_t row = blockIdx.x;
    float* p = S + row * NP;
    const int tid = threadIdx.x;
    float v[4];
    #pragma unroll
    for (int k = 0; k < 4; k++) v[k] = p[tid + k * 256];
    float m = fmaxf(fmaxf(v[0], v[1]), fmaxf(v[2], v[3]));
    m = block_reduce_max(m, red);
    float s = 0.f;
    #pragma unroll
    for (int k = 0; k < 4; k++) { v[k] = __expf(v[k] - m); s += v[k]; }
    s = block_reduce_sum(s, red);
    float inv = 1.0f / s;
    #pragma unroll
    for (int k = 0; k < 4; k++) p[tid + k * 256] = v[k] * inv;
}

// ---------------- msg[bt,4d+h,n] = sum_m P[bh,n,m] v[bt,4d+h,m] ----------------
__global__ __launch_bounds__(256)
void pv_kernel(const float* __restrict__ P, const float* __restrict__ V, float* __restrict__ MSG)
{
    __shared__ float Vs[16][68]; // Vs[mm][dd]
    __shared__ float Ps[16][68]; // Ps[mm][nn]
    const int bh = blockIdx.y, bt = bh >> 2, h = bh & 3;
    const int n0 = blockIdx.x * 64;
    const int tx = threadIdx.x, ty = threadIdx.y;
    const int tid = ty * 16 + tx;
    const int l_r = tid >> 2;        // 0..63
    const int l_m = (tid & 3) * 4;   // 0..12
    const float* Pb = P + (size_t)bh * NP * NP;
    float acc[4][4] = {};
    for (int m0 = 0; m0 < NP; m0 += 16) {
        float4 v4 = *(const float4*)&V[((size_t)bt * DM + 4 * l_r + h) * NP + m0 + l_m];
        Vs[l_m + 0][l_r] = v4.x; Vs[l_m + 1][l_r] = v4.y;
        Vs[l_m + 2][l_r] = v4.z; Vs[l_m + 3][l_r] = v4.w;
        float4 p4 = *(const float4*)&Pb[(size_t)(n0 + l_r) * NP + m0 + l_m];
        Ps[l_m + 0][l_r] = p4.x; Ps[l_m + 1][l_r] = p4.y;
        Ps[l_m + 2][l_r] = p4.z; Ps[l_m + 3][l_r] = p4.w;
        __syncthreads();
        #pragma unroll
        for (int mm = 0; mm < 16; mm++) {
            float4 a4 = *(const float4*)&Vs[mm][ty * 4];
            float4 b4 = *(const float4*)&Ps[mm][tx * 4];
            float av[4] = {a4.x, a4.y, a4.z, a4.w};
            float bv[4] = {b4.x, b4.y, b4.z, b4.w};
            #pragma unroll
            for (int i = 0; i < 4; i++)
                #pragma unroll
                for (int j = 0; j < 4; j++)
                    acc[i][j] = fmaf(av[i], bv[j], acc[i][j]);
        }
        __syncthreads();
    }
    #pragma unroll
    for (int i = 0; i < 4; i++)
        #pragma unroll
        for (int j = 0; j < 4; j++)
            MSG[((size_t)bt * DM + 4 * (ty * 4 + i) + h) * NP + n0 + tx * 4 + j] = acc[i][j];
}

// ---------------- BatchNorm (training) stats per (set, channel) over 2*NP values ----------------
__global__ __launch_bounds__(256)
void bn_stats_kernel(const float* __restrict__ Xc, float* __restrict__ stats, int C)
{
    __shared__ float red[256];
    const int s = blockIdx.x / C, c = blockIdx.x % C;
    const int tid = threadIdx.x;
    float sum = 0.f, sq = 0.f;
    for (int b = 0; b < 2; b++) {
        const float* p = Xc + ((size_t)(2 * s + b) * C + c) * NP;
        for (int j = tid; j < NP; j += 256) { float x = p[j]; sum += x; sq = fmaf(x, x, sq); }
    }
    sum = block_reduce_sum(sum, red);
    sq = block_reduce_sum(sq, red);
    if (tid == 0) {
        float mu = sum * (1.0f / 2048.0f);
        float var = sq * (1.0f / 2048.0f) - mu * mu;
        var = fmaxf(var, 0.f);
        stats[(size_t)(s * C + c) * 2 + 0] = mu;
        stats[(size_t)(s * C + c) * 2 + 1] = rsqrtf(var + 1e-5f);
    }
}

__global__ __launch_bounds__(256)
void bn_apply_relu_kernel(float* __restrict__ Xc, const float* __restrict__ stats,
                          const float* __restrict__ g, const float* __restrict__ be, int C)
{
    size_t idx = (size_t)blockIdx.x * 256 + threadIdx.x; // total BT*C*NP (exact)
    int c = (int)((idx / NP) % C);
    int s = (int)(idx / ((size_t)2 * C * NP));
    float mu = stats[(size_t)(s * C + c) * 2 + 0];
    float is = stats[(size_t)(s * C + c) * 2 + 1];
    float x = Xc[idx];
    x = g[c] * (x - mu) * is + be[c];
    Xc[idx] = fmaxf(x, 0.0f);
}

// ---------------- keypoint encoder ----------------
__global__ __launch_bounds__(256)
void kenc_input_kernel(const float* __restrict__ k0, const float* __restrict__ k1,
                       const float* __restrict__ s0, const float* __restrict__ s1,
                       float* __restrict__ Xk)
{
    int t = blockIdx.x * 256 + threadIdx.x; // 4096
    int bt = t >> 10, n = t & 1023;
    const float* kp = (bt < 2) ? k0 : k1;
    const float* sc = (bt < 2) ? s0 : s1;
    int b = bt & 1;
    float x = kp[((size_t)b * NP + n) * 2 + 0];
    float y = kp[((size_t)b * NP + n) * 2 + 1];
    const float fs = 640.0f * 0.7f;
    Xk[((size_t)bt * 3 + 0) * NP + n] = (x - 320.0f) / fs;
    Xk[((size_t)bt * 3 + 1) * NP + n] = (y - 240.0f) / fs;
    Xk[((size_t)bt * 3 + 2) * NP + n] = sc[(size_t)b * NP + n];
}

__global__ __launch_bounds__(256)
void kenc_conv_kernel(const float* __restrict__ W, const float* __restrict__ bias,
                      const float* __restrict__ Xin, float* __restrict__ Out,
                      int O, int I, const float* __restrict__ desc0, const float* __restrict__ desc1)
{
    int n = blockIdx.x * 256 + threadIdx.x;
    int o = blockIdx.y, bt = blockIdx.z;
    const float* x = Xin + (size_t)bt * I * NP + n;
    float acc = bias[o];
    for (int i = 0; i < I; i++) acc = fmaf(W[(size_t)o * I + i], x[(size_t)i * NP], acc);
    if (desc0) {
        const float* d = (bt < 2) ? desc0 : desc1;
        acc += d[((size_t)(bt & 1) * O + o) * NP + n];
    }
    Out[((size_t)bt * O + o) * NP + n] = acc;
}

// ---------------- final scores -> Z (ld 1025) ----------------
__global__ __launch_bounds__(256)
void final_scores_kernel(const float* __restrict__ M, float* __restrict__ Z)
{
    __shared__ float As[16][68], Bs[16][68];
    const int b = blockIdx.z;
    const int n0 = blockIdx.x * 64, m0 = blockIdx.y * 64;
    const int tx = threadIdx.x, ty = threadIdx.y;
    const int tid = ty * 16 + tx;
    const int ld_d = tid >> 4;
    const int ld_c = (tid & 15) * 4;
    float acc[4][4] = {};
    for (int d0 = 0; d0 < DM; d0 += 16) {
        float4 a4 = *(const float4*)&M[((size_t)b * DM + d0 + ld_d) * NP + n0 + ld_c];
        float4 b4 = *(const float4*)&M[((size_t)(2 + b) * DM + d0 + ld_d) * NP + m0 + ld_c];
        As[ld_d][ld_c + 0] = a4.x; As[ld_d][ld_c + 1] = a4.y;
        As[ld_d][ld_c + 2] = a4.z; As[ld_d][ld_c + 3] = a4.w;
        Bs[ld_d][ld_c + 0] = b4.x; Bs[ld_d][ld_c + 1] = b4.y;
        Bs[ld_d][ld_c + 2] = b4.z; Bs[ld_d][ld_c + 3] = b4.w;
        __syncthreads();
        #pragma unroll
        for (int kk = 0; kk < 16; kk++) {
            float4 aa = *(const float4*)&As[kk][ty * 4];
            float4 bb = *(const float4*)&Bs[kk][tx * 4];
            float av[4] = {aa.x, aa.y, aa.z, aa.w};
            float bv[4] = {bb.x, bb.y, bb.z, bb.w};
            #pragma unroll
            for (int i = 0; i < 4; i++)
                #pragma unroll
                for (int j = 0; j < 4; j++)
                    acc[i][j] = fmaf(av[i], bv[j], acc[i][j]);
        }
        __syncthreads();
    }
    float* Zb = Z + (size_t)b * 1025 * 1025;
    #pragma unroll
    for (int i = 0; i < 4; i++)
        #pragma unroll
        for (int j = 0; j < 4; j++)
            Zb[(size_t)(n0 + ty * 4 + i) * 1025 + m0 + tx * 4 + j] = acc[i][j] * 0.0625f;
}

__global__ void fill_bins_kernel(float* __restrict__ Z, const float* __restrict__ alpha_p)
{
    float a = *alpha_p;
    int t = blockIdx.x * 256 + threadIdx.x;
    if (t >= 2 * 1025) return;
    int b = t / 1025, i = t % 1025;
    float* Zb = Z + (size_t)b * 1025 * 1025;
    Zb[(size_t)1024 * 1025 + i] = a;
    Zb[(size_t)i * 1025 + 1024] = a;
}

__global__ void transpose_kernel(const float* __restrict__ Z, float* __restrict__ Zt)
{
    __shared__ float tile[32][33];
    const int b = blockIdx.z;
    const int m0 = blockIdx.x * 32, n0 = blockIdx.y * 32;
    const float* Zb = Z + (size_t)b * 1025 * 1025;
    float* Ztb = Zt + (size_t)b * 1025 * 1025;
    for (int r = threadIdx.y; r < 32; r += 8) {
        int n = n0 + r, m = m0 + threadIdx.x;
        if (n < 1025 && m < 1025) tile[r][threadIdx.x] = Zb[(size_t)n * 1025 + m];
    }
    __syncthreads();
    for (int r = threadIdx.y; r < 32; r += 8) {
        int m = m0 + r, n = n0 + threadIdx.x;
        if (m < 1025 && n < 1025) Ztb[(size_t)m * 1025 + n] = tile[threadIdx.x][r];
    }
}

__global__ void sink_init_kernel(float* __restrict__ u, float* __restrict__ v, float* __restrict__ logw)
{
    int t = blockIdx.x * 256 + threadIdx.x;
    if (t < 2050) { u[t] = 0.f; v[t] = 0.f; }
    if (t < 1025) logw[t] = (t < 1024) ? -LOG2048 : (LOG1024 - LOG2048);
}

// out[b,i] = logw[i] - LSE_j( Zm[b,i,j] + addv[b,j] )
__global__ __launch_bounds__(256)
void lse_kernel(const float* __restrict__ Zm, const float* __restrict__ addv,
                const float* __restrict__ logw, float* __restrict__ outv)
{
    __shared__ float red[256];
    const int row = blockIdx.x;
    const int b = row / 1025, i = row % 1025;
    const float* zr = Zm + (size_t)b * 1025 * 1025 + (size_t)i * 1025;
    const float* av = addv + (size_t)b * 1025;
    const int tid = threadIdx.x;
    float vals[5];
    #pragma unroll
    for (int k = 0; k < 4; k++) vals[k] = zr[tid + k * 256] + av[tid + k * 256];
    vals[4] = (tid == 0) ? (zr[1024] + av[1024]) : -3.4e38f;
    float m = vals[0];
    #pragma unroll
    for (int k = 1; k < 5; k++) m = fmaxf(m, vals[k]);
    m = block_reduce_max(m, red);
    float ssum = 0.f;
    #pragma unroll
    for (int k = 0; k < 4; k++) ssum += __expf(vals[k] - m);
    if (tid == 0) ssum += __expf(vals[4] - m);
    ssum = block_reduce_sum(ssum, red);
    if (tid == 0) outv[(size_t)b * 1025 + i] = logw[i] - (m + __logf(ssum));
}

__global__ void final_out_kernel(const float* __restrict__ Z, const float* __restrict__ u,
                                 const float* __restrict__ v, float* __restrict__ out)
{
    size_t t = (size_t)blockIdx.x * 256 + threadIdx.x;
    if (t >= (size_t)2 * 1025 * 1025) return;
    int b = (int)(t / (1025 * 1025));
    int r = (int)(t % (1025 * 1025));
    int n = r / 1025, m = r % 1025;
    out[t] = Z[t] + u[b * 1025 + n] + v[b * 1025 + m] + LOG2048;
}

// =======================================================================
extern "C" void kernel_launch(void* const* d_in, const int* in_sizes, int n_in,
                              void* d_out, int out_size, void* d_ws, size_t ws_size,
                              hipStream_t stream)
{
    const float* kpts0   = (const float*)d_in[0];
    const float* kpts1   = (const float*)d_in[1];
    const float* scores0 = (const float*)d_in[2];
    const float* scores1 = (const float*)d_in[3];
    const float* desc0   = (const float*)d_in[4];
    const float* desc1   = (const float*)d_in[5];
    const float* kenc_w0 = (const float*)d_in[6];
    const float* kenc_b0 = (const float*)d_in[7];
    const float* kenc_g0 = (const float*)d_in[8];
    const float* kenc_be0= (const float*)d_in[9];
    const float* kenc_w1 = (const float*)d_in[10];
    const float* kenc_b1 = (const float*)d_in[11];
    const float* kenc_g1 = (const float*)d_in[12];
    const float* kenc_be1= (const float*)d_in[13];
    const float* kenc_w2 = (const float*)d_in[14];
    const float* kenc_b2 = (const float*)d_in[15];
    const float* kenc_g2 = (const float*)d_in[16];
    const float* kenc_be2= (const float*)d_in[17];
    const float* kenc_w3 = (const float*)d_in[18];
    const float* kenc_b3 = (const float*)d_in[19];
    const float* proj_w  = (const float*)d_in[20];
    const float* proj_b  = (const float*)d_in[21];
    const float* merge_w = (const float*)d_in[22];
    const float* merge_b = (const float*)d_in[23];
    const float* mlp1_w  = (const float*)d_in[24];
    const float* mlp1_b  = (const float*)d_in[25];
    const float* bn_g    = (const float*)d_in[26];
    const float* bn_b    = (const float*)d_in[27];
    const float* mlp2_w  = (const float*)d_in[28];
    const float* mlp2_b  = (const float*)d_in[29];
    const float* final_w = (const float*)d_in[30];
    const float* final_b = (const float*)d_in[31];
    const float* bin_sc  = (const float*)d_in[32];

    float* ws = (float*)d_ws;
    float* X    = ws;                    // 4*256*1024   = 1048576
    float* Qb   = X    + 1048576;
    float* Kb   = Qb   + 1048576;
    float* Vb   = Kb   + 1048576;
    float* MSG  = Vb   + 1048576;
    float* MSG2 = MSG  + 1048576;
    float* Y2   = MSG2 + 1048576;        // 4*512*1024   = 2097152
    float* Sbuf = Y2   + 2097152;        // 16*1024*1024 = 16777216
    float* Zb   = Sbuf;                  // reuse S region after attention done
    float* Zt   = Sbuf + 2101252;
    float* stats= Sbuf + 16777216;       // 2048
    float* uvec = stats + 2048;          // 2050 (+pad)
    float* vvec = uvec + 2052;
    float* logw = vvec + 2052;           // 1025 (+pad)
    float* kencX= logw + 1028;           // 4*3*1024 = 12288

    dim3 tb2(16, 16);

    // -------- keypoint encoder (both sets batched as bt=0..3) --------
    kenc_input_kernel<<<16, 256, 0, stream>>>(kpts0, kpts1, scores0, scores1, kencX);
    kenc_conv_kernel<<<dim3(4, 32, 4), 256, 0, stream>>>(kenc_w0, kenc_b0, kencX, Qb, 32, 3, nullptr, nullptr);
    bn_stats_kernel<<<64, 256, 0, stream>>>(Qb, stats, 32);
    bn_apply_relu_kernel<<<512, 256, 0, stream>>>(Qb, stats, kenc_g0, kenc_be0, 32);
    kenc_conv_kernel<<<dim3(4, 64, 4), 256, 0, stream>>>(kenc_w1, kenc_b1, Qb, Kb, 64, 32, nullptr, nullptr);
    bn_stats_kernel<<<128, 256, 0, stream>>>(Kb, stats, 64);
    bn_apply_relu_kernel<<<1024, 256, 0, stream>>>(Kb, stats, kenc_g1, kenc_be1, 64);
    kenc_conv_kernel<<<dim3(4, 128, 4), 256, 0, stream>>>(kenc_w2, kenc_b2, Kb, Vb, 128, 64, nullptr, nullptr);
    bn_stats_kernel<<<256, 256, 0, stream>>>(Vb, stats, 128);
    bn_apply_relu_kernel<<<2048, 256, 0, stream>>>(Vb, stats, kenc_g2, kenc_be2, 128);
    kenc_conv_kernel<<<dim3(4, 256, 4), 256, 0, stream>>>(kenc_w3, kenc_b3, Vb, X, 256, 128, desc0, desc1);

    // -------- 18 GNN layers --------
    for (int l = 0; l < NL; l++) {
        int sx = (l & 1) ? 2 : 0;
        const float* pw = proj_w + (size_t)l * 3 * 65536;
        const float* pb = proj_b + (size_t)l * 3 * 256;
        gemm_conv_kernel<<<dim3(16, 4, 4), tb2, 0, stream>>>(pw,          pb,       X, nullptr, Qb, 256, 256, 256, 0, 0);
        gemm_conv_kernel<<<dim3(16, 4, 4), tb2, 0, stream>>>(pw + 65536,  pb + 256, X, nullptr, Kb, 256, 256, 256, sx, 0);
        gemm_conv_kernel<<<dim3(16, 4, 4), tb2, 0, stream>>>(pw + 131072, pb + 512, X, nullptr, Vb, 256, 256, 256, sx, 0);
        qk_kernel<<<dim3(16, 16, 16), tb2, 0, stream>>>(Qb, Kb, Sbuf);
        softmax_kernel<<<16 * 1024, 256, 0, stream>>>(Sbuf);
        pv_kernel<<<dim3(16, 16), tb2, 0, stream>>>(Sbuf, Vb, MSG);
        gemm_conv_kernel<<<dim3(16, 4, 4), tb2, 0, stream>>>(merge_w + (size_t)l * 65536, merge_b + (size_t)l * 256,
                                                             MSG, nullptr, MSG2, 256, 256, 256, 0, 0);
        gemm_conv_kernel<<<dim3(16, 8, 4), tb2, 0, stream>>>(mlp1_w + (size_t)l * 262144, mlp1_b + (size_t)l * 512,
                                                             X, MSG2, Y2, 512, 512, 256, 0, 0);
        bn_stats_kernel<<<1024, 256, 0, stream>>>(Y2, stats, 512);
        bn_apply_relu_kernel<<<8192, 256, 0, stream>>>(Y2, stats, bn_g + (size_t)l * 512, bn_b + (size_t)l * 512, 512);
        gemm_conv_kernel<<<dim3(16, 4, 4), tb2, 0, stream>>>(mlp2_w + (size_t)l * 131072, mlp2_b + (size_t)l * 256,
                                                             Y2, nullptr, X, 256, 512, 512, 0, 1);
    }

    // -------- final projection + scores + optimal transport --------
    gemm_conv_kernel<<<dim3(16, 4, 4), tb2, 0, stream>>>(final_w, final_b, X, nullptr, Qb, 256, 256, 256, 0, 0);
    final_scores_kernel<<<dim3(16, 16, 2), tb2, 0, stream>>>(Qb, Zb);
    fill_bins_kernel<<<9, 256, 0, stream>>>(Zb, bin_sc);
    transpose_kernel<<<dim3(33, 33, 2), dim3(32, 8), 0, stream>>>(Zb, Zt);
    sink_init_kernel<<<9, 256, 0, stream>>>(uvec, vvec, logw);
    for (int it = 0; it < 50; it++) {
        lse_kernel<<<2050, 256, 0, stream>>>(Zb, vvec, logw, uvec);
        lse_kernel<<<2050, 256, 0, stream>>>(Zt, uvec, logw, vvec);
    }
    final_out_kernel<<<8209, 256, 0, stream>>>(Zb, uvec, vvec, (float*)d_out);
}

// Round 2
// 2947.765 us; speedup vs baseline: 1.8277x; 1.8277x over previous
//
#include <hip/hip_runtime.h>
#include <hip/hip_bf16.h>
#include <math.h>

#define NP 1024
#define NL 18
#define LOG2048 7.6246189861593985f
#define LOG1024 6.9314718055994531f

typedef __attribute__((ext_vector_type(8))) short short8;
typedef __attribute__((ext_vector_type(4))) float f32x4;
typedef unsigned short u16;

__device__ __forceinline__ u16 f2b(float f) {
    __hip_bfloat16 h = __float2bfloat16(f);
    return *reinterpret_cast<u16*>(&h);
}
__device__ __forceinline__ float b2f(u16 u) {
    __hip_bfloat16 h;
    *reinterpret_cast<u16*>(&h) = u;
    return __bfloat162float(h);
}
__device__ __forceinline__ short8 ld8(const u16* p) { return *reinterpret_cast<const short8*>(p); }

// ---------------- block reductions (blockDim = 256) ----------------
__device__ __forceinline__ float block_reduce_max(float v, float* red) {
    int tid = threadIdx.x;
    red[tid] = v; __syncthreads();
    for (int s = 128; s > 0; s >>= 1) {
        if (tid < s) red[tid] = fmaxf(red[tid], red[tid + s]);
        __syncthreads();
    }
    float r = red[0]; __syncthreads();
    return r;
}
__device__ __forceinline__ float block_reduce_sum(float v, float* red) {
    int tid = threadIdx.x;
    red[tid] = v; __syncthreads();
    for (int s = 128; s > 0; s >>= 1) {
        if (tid < s) red[tid] += red[tid + s];
        __syncthreads();
    }
    float r = red[0]; __syncthreads();
    return r;
}

// ---------------- weight cast / permute ----------------
// mode 0: plain cast; mode 1: dst row r' <- src row ((r'&63)<<2)|(r'>>6)  (planar<-interleaved)
// mode 2: same permutation on columns
__global__ void castperm_kernel(const float* __restrict__ src, u16* __restrict__ dst,
                                int R, int C, int mode)
{
    size_t idx = (size_t)blockIdx.x * 256 + threadIdx.x;
    int rc = R * C;
    size_t mat = idx / rc; int rem = (int)(idx % rc);
    int r = rem / C, c = rem % C;
    if (mode == 1) r = ((r & 63) << 2) | (r >> 6);
    else if (mode == 2) c = ((c & 63) << 2) | (c >> 6);
    dst[idx] = f2b(src[mat * rc + (size_t)r * C + c]);
}

__global__ void permb_kernel(const float* __restrict__ src, float* __restrict__ dst)
{
    int idx = blockIdx.x * 256 + threadIdx.x; // 54*256
    int mat = idx >> 8, r = idx & 255;
    int o = ((r & 63) << 2) | (r >> 6);
    dst[idx] = src[mat * 256 + o];
}

// ---------------- desc -> X (transpose to [bt][n][256] f32) ----------------
__global__ void desc_t_kernel(const float* __restrict__ d0, const float* __restrict__ d1,
                              float* __restrict__ X)
{
    __shared__ float tile[32][33];
    const int bt = blockIdx.z, b = bt & 1;
    const float* d = (bt < 2) ? d0 : d1;
    const int c0 = blockIdx.x * 32, n0 = blockIdx.y * 32;
    for (int rr = threadIdx.y; rr < 32; rr += 8)
        tile[rr][threadIdx.x] = d[((size_t)b * 256 + c0 + rr) * NP + n0 + threadIdx.x];
    __syncthreads();
    for (int rr = threadIdx.y; rr < 32; rr += 8)
        X[((size_t)bt * NP + n0 + rr) * 256 + c0 + threadIdx.x] = tile[threadIdx.x][rr];
}

// ---------------- kenc first conv (3->32) ----------------
__global__ __launch_bounds__(256) void kenc1_kernel(
    const float* __restrict__ k0, const float* __restrict__ k1,
    const float* __restrict__ s0, const float* __restrict__ s1,
    const float* __restrict__ w, const float* __restrict__ bias, u16* __restrict__ A1)
{
    int t = blockIdx.x * 256 + threadIdx.x; // 4096*32
    int r = t >> 5, o = t & 31;
    int bt = r >> 10, n = r & 1023, b = bt & 1;
    const float* kp = (bt < 2) ? k0 : k1;
    const float* sc = (bt < 2) ? s0 : s1;
    float x0 = (kp[((size_t)b * NP + n) * 2 + 0] - 320.f) * (1.f / 448.f);
    float x1 = (kp[((size_t)b * NP + n) * 2 + 1] - 240.f) * (1.f / 448.f);
    float x2 = sc[(size_t)b * NP + n];
    float a = w[o * 3 + 0] * x0 + w[o * 3 + 1] * x1 + w[o * 3 + 2] * x2 + bias[o];
    A1[(size_t)r * 32 + o] = f2b(a);
}

// ---------------- BatchNorm ----------------
// small: one block per (set, channel), computes affine s1*x+s0 directly
__global__ __launch_bounds__(256) void bn_small_kernel(const u16* __restrict__ Xc, int C,
    const float* __restrict__ g, const float* __restrict__ be, float2* __restrict__ s01)
{
    __shared__ float red[256];
    const int s = blockIdx.x / C, c = blockIdx.x % C;
    const int tid = threadIdx.x;
    float sum = 0.f, sq = 0.f;
    const u16* p = Xc + (size_t)s * 2048 * C + c;
    for (int j = tid; j < 2048; j += 256) { float v = b2f(p[(size_t)j * C]); sum += v; sq = fmaf(v, v, sq); }
    sum = block_reduce_sum(sum, red);
    sq  = block_reduce_sum(sq, red);
    if (tid == 0) {
        float mu = sum * (1.f / 2048.f);
        float var = fmaxf(sq * (1.f / 2048.f) - mu * mu, 0.f);
        float s1 = g[c] * rsqrtf(var + 1e-5f);
        s01[s * C + c] = make_float2(s1, be[c] - s1 * mu);
    }
}

// big (C=512): coalesced partial sums, deterministic slots
__global__ __launch_bounds__(256) void bn_big_stats(const u16* __restrict__ Y, float2* __restrict__ part)
{
    __shared__ float rs[256], rq[256];
    const int tid = threadIdx.x, cl = tid & 63, sub = tid >> 6;
    const int ch = blockIdx.x, cg = blockIdx.y, s = blockIdx.z;
    const int c = cg * 64 + cl;
    float sum = 0.f, sq = 0.f;
    const u16* p = Y + ((size_t)s * 2048 + ch * 128 + sub) * 512 + c;
    for (int j = 0; j < 32; j++) { float v = b2f(p[(size_t)j * 4 * 512]); sum += v; sq = fmaf(v, v, sq); }
    rs[tid] = sum; rq[tid] = sq; __syncthreads();
    if (tid < 64) {
        sum = rs[tid] + rs[tid + 64] + rs[tid + 128] + rs[tid + 192];
        sq  = rq[tid] + rq[tid + 64] + rq[tid + 128] + rq[tid + 192];
        part[(((size_t)s * 8 + cg) * 16 + ch) * 64 + cl] = make_float2(sum, sq);
    }
}

__global__ void bn_big_finalize(const float2* __restrict__ part, const float* __restrict__ g,
                                const float* __restrict__ be, float2* __restrict__ s01)
{
    int idx = blockIdx.x * 256 + threadIdx.x; // 1024
    int s = idx >> 9, c = idx & 511;
    float sum = 0.f, sq = 0.f;
    for (int ch = 0; ch < 16; ch++) {
        float2 p = part[(((size_t)s * 8 + (c >> 6)) * 16 + ch) * 64 + (c & 63)];
        sum += p.x; sq += p.y;
    }
    float mu = sum * (1.f / 2048.f);
    float var = fmaxf(sq * (1.f / 2048.f) - mu * mu, 0.f);
    float s1 = g[c] * rsqrtf(var + 1e-5f);
    s01[idx] = make_float2(s1, be[c] - s1 * mu);
}

__global__ __launch_bounds__(256) void bn_apply_kernel(u16* __restrict__ Xc,
    const float2* __restrict__ s01, int C)
{
    size_t idx = (size_t)blockIdx.x * 256 + threadIdx.x;
    int c = (int)(idx % C);
    int s = (int)(idx / ((size_t)2048 * C));
    float2 p = s01[s * C + c];
    float v = fmaf(p.x, b2f(Xc[idx]), p.y);
    Xc[idx] = f2b(fmaxf(v, 0.f));
}

// ---------------- MFMA conv GEMM: Out[r][o] = act( sum_k W[o][k] * B(r^xor, k) + bias[o] )
// B rows: flat 4096 (bt*1024+n); k<split from B1 (ld split) else B2 (ld K-split)
// MODE 0: bf16 T-layout out [r][Cout]; MODE 1: bf16 N-layout out [bt][o][n]; MODE 2: f32 X += and Xb bf16
template<int K, int MODE>
__global__ __launch_bounds__(256) void gemm_mfma(
    const u16* __restrict__ W, const float* __restrict__ bias,
    const u16* __restrict__ B1, const u16* __restrict__ B2, int split,
    int srcXor, u16* __restrict__ outB, float* __restrict__ Xf, u16* __restrict__ Xb, int Cout)
{
    const int tid = threadIdx.x;
    const int wv = tid >> 6, lane = tid & 63, l15 = lane & 15, q = lane >> 4;
    const int r0 = blockIdx.x * 64, o0 = blockIdx.y * 64;
    const int wo = (wv & 1) * 32, wn = (wv >> 1) * 32;
    f32x4 acc[2][2] = {};
    const int oa0 = o0 + wo + l15, oa1 = oa0 + 16;
    const int rb0 = (r0 + wn + l15) ^ srcXor, rb1 = (r0 + wn + 16 + l15) ^ srcXor;
    for (int k0 = 0; k0 < K; k0 += 32) {
        const int k = k0 + q * 8;
        short8 a0 = ld8(W + (size_t)oa0 * K + k);
        short8 a1 = ld8(W + (size_t)oa1 * K + k);
        const u16* bp; int ld, kk;
        if (k0 < split) { bp = B1; ld = split; kk = k; }
        else            { bp = B2; ld = K - split; kk = k - split; }
        short8 b0 = ld8(bp + (size_t)rb0 * ld + kk);
        short8 b1 = ld8(bp + (size_t)rb1 * ld + kk);
        acc[0][0] = __builtin_amdgcn_mfma_f32_16x16x32_bf16(a0, b0, acc[0][0], 0, 0, 0);
        acc[0][1] = __builtin_amdgcn_mfma_f32_16x16x32_bf16(a0, b1, acc[0][1], 0, 0, 0);
        acc[1][0] = __builtin_amdgcn_mfma_f32_16x16x32_bf16(a1, b0, acc[1][0], 0, 0, 0);
        acc[1][1] = __builtin_amdgcn_mfma_f32_16x16x32_bf16(a1, b1, acc[1][1], 0, 0, 0);
    }
    #pragma unroll
    for (int i = 0; i < 2; i++) {
        const int ob = o0 + wo + i * 16 + q * 4;
        f32x4 bi = *reinterpret_cast<const f32x4*>(bias + ob);
        #pragma unroll
        for (int j = 0; j < 2; j++) {
            const int rr = r0 + wn + j * 16 + l15;
            if (MODE == 0) {
                ushort4 pk;
                pk.x = f2b(acc[i][j][0] + bi[0]);
                pk.y = f2b(acc[i][j][1] + bi[1]);
                pk.z = f2b(acc[i][j][2] + bi[2]);
                pk.w = f2b(acc[i][j][3] + bi[3]);
                *reinterpret_cast<ushort4*>(outB + (size_t)rr * Cout + ob) = pk;
            } else if (MODE == 1) {
                const int bt = rr >> 10, n = rr & 1023;
                #pragma unroll
                for (int r = 0; r < 4; r++)
                    outB[((size_t)bt * Cout + ob + r) * NP + n] = f2b(acc[i][j][r] + bi[r]);
            } else {
                float* xp = Xf + (size_t)rr * Cout + ob;
                f32x4 xo = *reinterpret_cast<f32x4*>(xp);
                #pragma unroll
                for (int r = 0; r < 4; r++) xo[r] += acc[i][j][r] + bi[r];
                *reinterpret_cast<f32x4*>(xp) = xo;
                ushort4 pk;
                pk.x = f2b(xo[0]); pk.y = f2b(xo[1]); pk.z = f2b(xo[2]); pk.w = f2b(xo[3]);
                *reinterpret_cast<ushort4*>(Xb + (size_t)rr * Cout + ob) = pk;
            }
        }
    }
}

// ---------------- attention / scores MFMA ----------------
// MODE 0: qk  (A=Qt,B=Kt head-planar, f32 out S[z], ld 1024)
// MODE 1: pv  (A=P bf16-in-f32-rows ld2048, B=Vp plane, bf16 out MSGT)
// MODE 2: scores (plain, f32 out ld 1025)
template<int K, int MODE>
__global__ __launch_bounds__(256) void attn_mfma(
    const u16* __restrict__ A, const u16* __restrict__ Bm,
    float* __restrict__ outF, u16* __restrict__ outB, float scale)
{
    const int tid = threadIdx.x;
    const int wv = tid >> 6, lane = tid & 63, l15 = lane & 15, q = lane >> 4;
    const int z = blockIdx.z;
    const int m0 = blockIdx.x * 64 + (wv & 1) * 32;
    const int n0 = blockIdx.y * 64 + (wv >> 1) * 32;
    size_t aBase, bBase, oBase; int aLd, bLd, oLd;
    if (MODE == 0) {
        const int bt = z >> 2, h = z & 3;
        aBase = (size_t)bt * NP * 256 + 64 * h; aLd = 256;
        bBase = aBase; bLd = 256;
        oBase = (size_t)z * NP * NP; oLd = NP;
    } else if (MODE == 1) {
        const int bt = z >> 2, h = z & 3;
        aBase = (size_t)z * NP * 2048; aLd = 2048;
        bBase = ((size_t)bt * 256 + 64 * h) * NP; bLd = NP;
        oBase = (size_t)bt * NP * 256 + 64 * h; oLd = 256;
    } else {
        aBase = (size_t)z * NP * 256; aLd = 256;
        bBase = (size_t)z * NP * 256; bLd = 256;
        oBase = (size_t)z * 1025 * 1025; oLd = 1025;
    }
    f32x4 acc[2][2] = {};
    const int ma0 = m0 + l15, ma1 = ma0 + 16;
    const int nb0 = n0 + l15, nb1 = nb0 + 16;
    for (int k0 = 0; k0 < K; k0 += 32) {
        const int k = k0 + q * 8;
        short8 a0 = ld8(A + aBase + (size_t)ma0 * aLd + k);
        short8 a1 = ld8(A + aBase + (size_t)ma1 * aLd + k);
        short8 b0 = ld8(Bm + bBase + (size_t)nb0 * bLd + k);
        short8 b1 = ld8(Bm + bBase + (size_t)nb1 * bLd + k);
        acc[0][0] = __builtin_amdgcn_mfma_f32_16x16x32_bf16(a0, b0, acc[0][0], 0, 0, 0);
        acc[0][1] = __builtin_amdgcn_mfma_f32_16x16x32_bf16(a0, b1, acc[0][1], 0, 0, 0);
        acc[1][0] = __builtin_amdgcn_mfma_f32_16x16x32_bf16(a1, b0, acc[1][0], 0, 0, 0);
        acc[1][1] = __builtin_amdgcn_mfma_f32_16x16x32_bf16(a1, b1, acc[1][1], 0, 0, 0);
    }
    #pragma unroll
    for (int i = 0; i < 2; i++)
        #pragma unroll
        for (int j = 0; j < 2; j++)
            #pragma unroll
            for (int r = 0; r < 4; r++) {
                const int row = m0 + i * 16 + q * 4 + r;
                const int col = n0 + j * 16 + l15;
                if (MODE == 1) outB[oBase + (size_t)row * oLd + col] = f2b(acc[i][j][r]);
                else outF[oBase + (size_t)row * oLd + col] = acc[i][j][r] * scale;
            }
}

// ---------------- softmax over last dim (1024), f32 in, bf16 out in place ----------------
__global__ __launch_bounds__(256) void softmax_kernel(float* __restrict__ S)
{
    __shared__ float red[256];
    float* p = S + (size_t)blockIdx.x * NP;
    const int tid = threadIdx.x;
    f32x4 v = *reinterpret_cast<f32x4*>(p + tid * 4);
    float m = fmaxf(fmaxf(v[0], v[1]), fmaxf(v[2], v[3]));
    m = block_reduce_max(m, red);
    float e0 = __expf(v[0] - m), e1 = __expf(v[1] - m), e2 = __expf(v[2] - m), e3 = __expf(v[3] - m);
    float ss = block_reduce_sum(e0 + e1 + e2 + e3, red);
    float inv = 1.0f / ss;
    ushort4 pk;
    pk.x = f2b(e0 * inv); pk.y = f2b(e1 * inv); pk.z = f2b(e2 * inv); pk.w = f2b(e3 * inv);
    reinterpret_cast<ushort4*>(p)[tid] = pk;
}

// ---------------- sinkhorn ----------------
__global__ void fill_bins_kernel(float* __restrict__ Z, const float* __restrict__ alpha_p)
{
    float a = *alpha_p;
    int t = blockIdx.x * 256 + threadIdx.x;
    if (t >= 2 * 1025) return;
    int b = t / 1025, i = t % 1025;
    float* Zb = Z + (size_t)b * 1025 * 1025;
    Zb[(size_t)1024 * 1025 + i] = a;
    Zb[(size_t)i * 1025 + 1024] = a;
}

__global__ void sink_init_kernel(float* __restrict__ u, float* __restrict__ v, float* __restrict__ logw)
{
    int t = blockIdx.x * 256 + threadIdx.x;
    if (t < 2050) { u[t] = 0.f; v[t] = 0.f; }
    if (t < 1025) logw[t] = (t < 1024) ? -LOG2048 : (LOG1024 - LOG2048);
}

__global__ __launch_bounds__(256) void lse_kernel(const float* __restrict__ Zm, const float* __restrict__ addv,
                const float* __restrict__ logw, float* __restrict__ outv)
{
    __shared__ float red[256];
    const int row = blockIdx.x;
    const int b = row / 1025, i = row % 1025;
    const float* zr = Zm + (size_t)b * 1025 * 1025 + (size_t)i * 1025;
    const float* av = addv + (size_t)b * 1025;
    const int tid = threadIdx.x;
    float vals[5];
    #pragma unroll
    for (int k = 0; k < 4; k++) vals[k] = zr[tid + k * 256] + av[tid + k * 256];
    vals[4] = (tid == 0) ? (zr[1024] + av[1024]) : -3.4e38f;
    float m = vals[0];
    #pragma unroll
    for (int k = 1; k < 5; k++) m = fmaxf(m, vals[k]);
    m = block_reduce_max(m, red);
    float ssum = 0.f;
    #pragma unroll
    for (int k = 0; k < 4; k++) ssum += __expf(vals[k] - m);
    if (tid == 0) ssum += __expf(vals[4] - m);
    ssum = block_reduce_sum(ssum, red);
    if (tid == 0) outv[(size_t)b * 1025 + i] = logw[i] - (m + __logf(ssum));
}

__global__ void final_out_kernel(const float* __restrict__ Z, const float* __restrict__ u,
                                 const float* __restrict__ v, float* __restrict__ out)
{
    size_t t = (size_t)blockIdx.x * 256 + threadIdx.x;
    if (t >= (size_t)2 * 1025 * 1025) return;
    int b = (int)(t / (1025 * 1025));
    int r = (int)(t % (1025 * 1025));
    int n = r / 1025, m = r % 1025;
    out[t] = Z[t] + u[b * 1025 + n] + v[b * 1025 + m] + LOG2048;
}

// =======================================================================
extern "C" void kernel_launch(void* const* d_in, const int* in_sizes, int n_in,
                              void* d_out, int out_size, void* d_ws, size_t ws_size,
                              hipStream_t stream)
{
    (void)in_sizes; (void)n_in; (void)out_size; (void)ws_size;
    const float* kpts0   = (const float*)d_in[0];
    const float* kpts1   = (const float*)d_in[1];
    const float* scores0 = (const float*)d_in[2];
    const float* scores1 = (const float*)d_in[3];
    const float* desc0   = (const float*)d_in[4];
    const float* desc1   = (const float*)d_in[5];
    const float* kenc_w0 = (const float*)d_in[6];
    const float* kenc_b0 = (const float*)d_in[7];
    const float* kenc_g0 = (const float*)d_in[8];
    const float* kenc_be0= (const float*)d_in[9];
    const float* kenc_w1 = (const float*)d_in[10];
    const float* kenc_b1 = (const float*)d_in[11];
    const float* kenc_g1 = (const float*)d_in[12];
    const float* kenc_be1= (const float*)d_in[13];
    const float* kenc_w2 = (const float*)d_in[14];
    const float* kenc_b2 = (const float*)d_in[15];
    const float* kenc_g2 = (const float*)d_in[16];
    const float* kenc_be2= (const float*)d_in[17];
    const float* kenc_w3 = (const float*)d_in[18];
    const float* kenc_b3 = (const float*)d_in[19];
    const float* proj_w  = (const float*)d_in[20];
    const float* proj_b  = (const float*)d_in[21];
    const float* merge_w = (const float*)d_in[22];
    const float* merge_b = (const float*)d_in[23];
    const float* mlp1_w  = (const float*)d_in[24];
    const float* mlp1_b  = (const float*)d_in[25];
    const float* bn_g    = (const float*)d_in[26];
    const float* bn_b    = (const float*)d_in[27];
    const float* mlp2_w  = (const float*)d_in[28];
    const float* mlp2_b  = (const float*)d_in[29];
    const float* final_w = (const float*)d_in[30];
    const float* final_b = (const float*)d_in[31];
    const float* bin_sc  = (const float*)d_in[32];

    char* base = (char*)d_ws;
    size_t off = 0;
    auto alloc = [&](size_t bytes) -> void* {
        void* p = base + off;
        off = (off + bytes + 255) & ~(size_t)255;
        return p;
    };
    float* S     = (float*)alloc((size_t)16 * 1024 * 1024 * 4);   // S / P / Z region (64MB)
    float* X     = (float*)alloc((size_t)4 * NP * 256 * 4);
    u16*  Xb     = (u16*) alloc((size_t)4 * NP * 256 * 2);
    u16*  Qt     = (u16*) alloc((size_t)4 * NP * 256 * 2);
    u16*  Kt     = (u16*) alloc((size_t)4 * NP * 256 * 2);
    u16*  Vp     = (u16*) alloc((size_t)4 * NP * 256 * 2);
    u16*  MSGT   = (u16*) alloc((size_t)4 * NP * 256 * 2);
    u16*  MSG2T  = (u16*) alloc((size_t)4 * NP * 256 * 2);
    u16*  Y2T    = (u16*) alloc((size_t)4 * NP * 512 * 2);
    u16*  FT     = (u16*) alloc((size_t)4 * NP * 256 * 2);
    u16*  Wproj  = (u16*) alloc((size_t)54 * 65536 * 2);
    u16*  Wmerge = (u16*) alloc((size_t)18 * 65536 * 2);
    u16*  Wmlp1  = (u16*) alloc((size_t)18 * 262144 * 2);
    u16*  Wmlp2  = (u16*) alloc((size_t)18 * 131072 * 2);
    u16*  Wfin   = (u16*) alloc((size_t)65536 * 2);
    u16*  Wk1    = (u16*) alloc((size_t)64 * 32 * 2);
    u16*  Wk2    = (u16*) alloc((size_t)128 * 64 * 2);
    u16*  Wk3    = (u16*) alloc((size_t)256 * 128 * 2);
    float* pbp   = (float*)alloc((size_t)54 * 256 * 4);
    float2* part = (float2*)alloc((size_t)16384 * 8);
    float2* s01  = (float2*)alloc((size_t)1024 * 8);
    u16*  A1     = (u16*) alloc((size_t)4096 * 32 * 2);
    u16*  A2     = (u16*) alloc((size_t)4096 * 64 * 2);
    u16*  A3     = (u16*) alloc((size_t)4096 * 128 * 2);
    float* uvec  = (float*)alloc(2052 * 4);
    float* vvec  = (float*)alloc(2052 * 4);
    float* logw  = (float*)alloc(1028 * 4);
    float* Zb = S;
    float* Zt = (float*)((char*)S + (((size_t)2 * 1025 * 1025 * 4 + 255) & ~(size_t)255));

    // -------- weights: cast + permute --------
    castperm_kernel<<<54 * 65536 / 256, 256, 0, stream>>>(proj_w, Wproj, 256, 256, 1);
    castperm_kernel<<<18 * 65536 / 256, 256, 0, stream>>>(merge_w, Wmerge, 256, 256, 2);
    castperm_kernel<<<18 * 262144 / 256, 256, 0, stream>>>(mlp1_w, Wmlp1, 512, 512, 0);
    castperm_kernel<<<18 * 131072 / 256, 256, 0, stream>>>(mlp2_w, Wmlp2, 256, 512, 0);
    castperm_kernel<<<65536 / 256, 256, 0, stream>>>(final_w, Wfin, 256, 256, 0);
    castperm_kernel<<<2048 / 256, 256, 0, stream>>>(kenc_w1, Wk1, 64, 32, 0);
    castperm_kernel<<<8192 / 256, 256, 0, stream>>>(kenc_w2, Wk2, 128, 64, 0);
    castperm_kernel<<<32768 / 256, 256, 0, stream>>>(kenc_w3, Wk3, 256, 128, 0);
    permb_kernel<<<54, 256, 0, stream>>>(proj_b, pbp);
    desc_t_kernel<<<dim3(8, 32, 4), dim3(32, 8), 0, stream>>>(desc0, desc1, X);

    // -------- keypoint encoder --------
    kenc1_kernel<<<512, 256, 0, stream>>>(kpts0, kpts1, scores0, scores1, kenc_w0, kenc_b0, A1);
    bn_small_kernel<<<64, 256, 0, stream>>>(A1, 32, kenc_g0, kenc_be0, s01);
    bn_apply_kernel<<<512, 256, 0, stream>>>(A1, s01, 32);
    gemm_mfma<32, 0><<<dim3(64, 1), 256, 0, stream>>>(Wk1, kenc_b1, A1, A1, 32, 0, A2, nullptr, nullptr, 64);
    bn_small_kernel<<<128, 256, 0, stream>>>(A2, 64, kenc_g1, kenc_be1, s01);
    bn_apply_kernel<<<1024, 256, 0, stream>>>(A2, s01, 64);
    gemm_mfma<64, 0><<<dim3(64, 2), 256, 0, stream>>>(Wk2, kenc_b2, A2, A2, 64, 0, A3, nullptr, nullptr, 128);
    bn_small_kernel<<<256, 256, 0, stream>>>(A3, 128, kenc_g2, kenc_be2, s01);
    bn_apply_kernel<<<2048, 256, 0, stream>>>(A3, s01, 128);
    gemm_mfma<128, 2><<<dim3(64, 4), 256, 0, stream>>>(Wk3, kenc_b3, A3, A3, 128, 0, nullptr, X, Xb, 256);

    // -------- 18 GNN layers --------
    for (int l = 0; l < NL; l++) {
        int sx = (l & 1) ? 2048 : 0; // flat-row xor for cross attention (bt ^ 2)
        const u16* wq = Wproj + (size_t)(l * 3 + 0) * 65536;
        const u16* wk = Wproj + (size_t)(l * 3 + 1) * 65536;
        const u16* wv = Wproj + (size_t)(l * 3 + 2) * 65536;
        const float* bq = pbp + (l * 3 + 0) * 256;
        const float* bk = pbp + (l * 3 + 1) * 256;
        const float* bv = pbp + (l * 3 + 2) * 256;
        gemm_mfma<256, 0><<<dim3(64, 4), 256, 0, stream>>>(wq, bq, Xb, Xb, 256, 0,  Qt, nullptr, nullptr, 256);
        gemm_mfma<256, 0><<<dim3(64, 4), 256, 0, stream>>>(wk, bk, Xb, Xb, 256, sx, Kt, nullptr, nullptr, 256);
        gemm_mfma<256, 1><<<dim3(64, 4), 256, 0, stream>>>(wv, bv, Xb, Xb, 256, sx, Vp, nullptr, nullptr, 256);
        attn_mfma<64, 0><<<dim3(16, 16, 16), 256, 0, stream>>>(Qt, Kt, S, nullptr, 0.125f);
        softmax_kernel<<<16384, 256, 0, stream>>>(S);
        attn_mfma<1024, 1><<<dim3(16, 1, 16), 256, 0, stream>>>((const u16*)S, Vp, nullptr, MSGT, 1.f);
        gemm_mfma<256, 0><<<dim3(64, 4), 256, 0, stream>>>(Wmerge + (size_t)l * 65536, merge_b + l * 256,
                                                           MSGT, MSGT, 256, 0, MSG2T, nullptr, nullptr, 256);
        gemm_mfma<512, 0><<<dim3(64, 8), 256, 0, stream>>>(Wmlp1 + (size_t)l * 262144, mlp1_b + l * 512,
                                                           Xb, MSG2T, 256, 0, Y2T, nullptr, nullptr, 512);
        bn_big_stats<<<dim3(16, 8, 2), 256, 0, stream>>>(Y2T, part);
        bn_big_finalize<<<4, 256, 0, stream>>>(part, bn_g + l * 512, bn_b + l * 512, s01);
        bn_apply_kernel<<<8192, 256, 0, stream>>>(Y2T, s01, 512);
        gemm_mfma<512, 2><<<dim3(64, 4), 256, 0, stream>>>(Wmlp2 + (size_t)l * 131072, mlp2_b + l * 256,
                                                           Y2T, Y2T, 512, 0, nullptr, X, Xb, 256);
    }

    // -------- final projection + scores + optimal transport --------
    gemm_mfma<256, 0><<<dim3(64, 4), 256, 0, stream>>>(Wfin, final_b, Xb, Xb, 256, 0, FT, nullptr, nullptr, 256);
    attn_mfma<256, 2><<<dim3(16, 16, 2), 256, 0, stream>>>(FT, FT + (size_t)2 * NP * 256, Zb, nullptr, 0.0625f);
    attn_mfma<256, 2><<<dim3(16, 16, 2), 256, 0, stream>>>(FT + (size_t)2 * NP * 256, FT, Zt, nullptr, 0.0625f);
    fill_bins_kernel<<<9, 256, 0, stream>>>(Zb, bin_sc);
    fill_bins_kernel<<<9, 256, 0, stream>>>(Zt, bin_sc);
    sink_init_kernel<<<9, 256, 0, stream>>>(uvec, vvec, logw);
    for (int it = 0; it < 50; it++) {
        lse_kernel<<<2050, 256, 0, stream>>>(Zb, vvec, logw, uvec);
        lse_kernel<<<2050, 256, 0, stream>>>(Zt, uvec, logw, vvec);
    }
    final_out_kernel<<<8209, 256, 0, stream>>>(Zb, uvec, vvec, (float*)d_out);
}